// Round 5
// baseline (12300.065 us; speedup 1.0000x reference)
//
#include <hip/hip_runtime.h>

// RNNModel: B=64, T=512, D_IN=256, H=1024, L=3, D_OUT=128 (all fp32)
// R5: paired-octet recur. Each WG serves two independent 8-batch octets (A/B)
//     and interleaves them so each octet's flag/stage latency hides under the
//     other's matvec. W slice (2n x 32k per thread) lives in REGISTERS (no Wl
//     LDS reads). 256 WGs x 512 thr, LDS 81.25KB, 5 barriers / 2 steps.
#define NB   64
#define NT   512
#define DIN  256
#define NH   1024
#define DOUT 128

#define HS_STR 1028   // hs row stride (floats)
#define RD_STR 136    // red row stride (floats)

typedef float f4 __attribute__((ext_vector_type(4)));
typedef float f2 __attribute__((ext_vector_type(2)));
typedef unsigned short bfr;   // raw bf16 storage

__device__ __forceinline__ float b2f(bfr u) {
    union { unsigned u; float f; } v; v.u = ((unsigned)u) << 16; return v.f;
}
__device__ __forceinline__ bfr f2b(float f) {   // round-to-nearest-even
    union { float f; unsigned u; } v; v.f = f;
    unsigned r = v.u + 0x7FFFu + ((v.u >> 16) & 1u);
    return (bfr)(r >> 16);
}

template <typename T> __device__ __forceinline__ f4 load4(const T* p);
template <> __device__ __forceinline__ f4 load4<float>(const float* p) { return *(const f4*)p; }
template <> __device__ __forceinline__ f4 load4<bfr>(const bfr* p) {
    ushort4 u = *(const ushort4*)p;
    f4 r; r[0] = b2f(u.x); r[1] = b2f(u.y); r[2] = b2f(u.z); r[3] = b2f(u.w); return r;
}
template <typename T> __device__ __forceinline__ void store1(T* p, float v);
template <> __device__ __forceinline__ void store1<float>(float* p, float v) { *p = v; }
template <> __device__ __forceinline__ void store1<bfr>(bfr* p, float v) { *p = f2b(v); }
template <typename T> __device__ __forceinline__ float load1(const T* p);
template <> __device__ __forceinline__ float load1<float>(const float* p) { return *p; }
template <> __device__ __forceinline__ float load1<bfr>(const bfr* p) { return b2f(*p); }

// ===================== input projection GEMM (unchanged, passes) ===============
template <int K, int LOG2CT, typename TA, typename TO>
__global__ __launch_bounds__(256)
void proj_kernel(const TA* __restrict__ A, const float* __restrict__ W,
                 const float* __restrict__ bih, const float* __restrict__ bhh,
                 TO* __restrict__ out, int tOff)
{
    __shared__ float As[16][68];
    __shared__ float Ws[16][68];
    const int tid = threadIdx.x;
    const int CTM = (1 << LOG2CT) - 1;
    const int m0 = (blockIdx.x >> 4) << 6;
    const int n0 = (blockIdx.x & 15) << 6;
    const int tm = tid & 15, tn = tid >> 4;
    const int lr = tid >> 2, lc = tid & 3;

    const int rA = m0 + lr;
    const long mrowA = (long)(rA >> LOG2CT) * NT + tOff + (rA & CTM);

    float acc[4][4] = {};
    for (int k0 = 0; k0 < K; k0 += 16) {
        f4 av = load4<TA>(&A[mrowA * K + k0 + lc * 4]);
        f4 wv = *(const f4*)&W[(n0 + lr) * K + k0 + lc * 4];
        __syncthreads();
        #pragma unroll
        for (int j = 0; j < 4; ++j) {
            As[lc * 4 + j][lr] = av[j];
            Ws[lc * 4 + j][lr] = wv[j];
        }
        __syncthreads();
        #pragma unroll
        for (int k = 0; k < 16; ++k) {
            f4 a = *(const f4*)&As[k][tm * 4];
            f4 w = *(const f4*)&Ws[k][tn * 4];
            #pragma unroll
            for (int i = 0; i < 4; ++i)
                #pragma unroll
                for (int j = 0; j < 4; ++j)
                    acc[i][j] += a[i] * w[j];
        }
    }
    #pragma unroll
    for (int j = 0; j < 4; ++j) {
        const int n = n0 + tn * 4 + j;
        const float bias = bih[n] + bhh[n];
        #pragma unroll
        for (int i = 0; i < 4; ++i)
            store1<TO>(&out[(long)(m0 + tm * 4 + i) * NH + n], acc[i][j] + bias);
    }
}

// ===================== chunk copy-back (Paths B/C) =====================
template <typename TP, int L2CT>
__global__ __launch_bounds__(256)
void copyback_kernel(const TP* __restrict__ Q, TP* __restrict__ P, int tOff)
{
    const int r = blockIdx.x, tid = threadIdx.x;
    const int b = r >> L2CT, t = r & ((1 << L2CT) - 1);
    const TP* q = Q + (long)r * NH;
    TP* p = P + ((long)b * NT + tOff + t) * NH;
    #pragma unroll
    for (int j = 0; j < 4; ++j) p[tid + j * 256] = q[tid + j * 256];
}

// ===================== recurrent layer (cooperative, 256 WGs x 512 thr) =========
// WG set s = wg>>6 serves octet A (batches 16s..16s+7) and B (16s+8..16s+15),
// n-slice nBase = (wg&63)*16. Thread (tk,tn,tb): tk=tid>>4 k-chunk [32k),
// tn=(tid>>1)&7 owns 2 n-rows (in regs), tb=tid&1 owns 4 of 8 batch rows.
// Interleave: matvecA,pubA, matvecB,pubB, poll(A,B), stage(A,B).
template <typename TP>
__global__ __launch_bounds__(512)
void recur_kernel(const float* __restrict__ Whh, TP* __restrict__ P,
                  float* __restrict__ Hring, unsigned* __restrict__ sy)
{
    __shared__ float hsA[8 * HS_STR];    // 32.9 KB  h state, octet A
    __shared__ float hsB[8 * HS_STR];    // 32.9 KB  h state, octet B
    __shared__ float red[32 * RD_STR];   // 17.0 KB  k-split partials

    const int tid  = threadIdx.x;
    const int wg   = blockIdx.x;
    const int nBase = (wg & 63) << 4;
    const int set   = wg >> 6;           // [0,4)
    const int rank  = wg & 63;
    const int lane  = tid & 63;
    const int tk = tid >> 4;             // [0,32)
    const int tn = (tid >> 1) & 7;       // [0,8)
    const int tb = tid & 1;              // [0,2)
    const int bl = tid >> 4;             // reduce role (tid<128): [0,8)
    const int nl = tid & 15;

    // ---- W slice into registers: rows nBase+tn*2+{0,1}, cols [tk*32, +32) ----
    float w0[32], w1[32];
    {
        const float* p0 = &Whh[(nBase + tn * 2 + 0) * NH + tk * 32];
        const float* p1 = &Whh[(nBase + tn * 2 + 1) * NH + tk * 32];
        #pragma unroll
        for (int i = 0; i < 8; ++i) {
            *(f4*)&w0[i * 4] = *(const f4*)&p0[i * 4];
            *(f4*)&w1[i * 4] = *(const f4*)&p1[i * 4];
        }
    }
    for (int i = tid; i < 8 * HS_STR; i += 512) { hsA[i] = 0.f; hsB[i] = 0.f; }
    __syncthreads();

    #pragma unroll 1
    for (int ts = 0; ts < NT; ++ts) {
        const unsigned tgt = (unsigned)(ts + 1);

        // ================= octet A =================
        float preA = 0.f; TP* ppA = nullptr;
        if (tid < 128) {
            ppA = &P[((long)(set * 16 + bl) * NT + ts) * NH + nBase + nl];
            preA = load1<TP>(ppA);
        }
        {
            float acc[4][2] = {};
            #pragma unroll
            for (int kk = 0; kk < 8; ++kk) {
                f4 hv[4];
                #pragma unroll
                for (int i = 0; i < 4; ++i)
                    hv[i] = *(const f4*)&hsA[(tb * 4 + i) * HS_STR + tk * 32 + kk * 4];
                #pragma unroll
                for (int c = 0; c < 4; ++c)
                    #pragma unroll
                    for (int i = 0; i < 4; ++i) {
                        acc[i][0] += hv[i][c] * w0[kk * 4 + c];
                        acc[i][1] += hv[i][c] * w1[kk * 4 + c];
                    }
            }
            #pragma unroll
            for (int i = 0; i < 4; ++i) {
                red[tk * RD_STR + (tb * 4 + i) * 16 + tn * 2 + 0] = acc[i][0];
                red[tk * RD_STR + (tb * 4 + i) * 16 + tn * 2 + 1] = acc[i][1];
            }
        }
        __syncthreads();                                   // bar1
        if (tid < 128) {
            float s = 0.f;
            #pragma unroll
            for (int q = 0; q < 32; ++q) s += red[q * RD_STR + tid];
            const float h = fmaxf(s + preA, 0.f);
            store1<TP>(ppA, h);
            __hip_atomic_store(&Hring[((long)(ts & 1) << 16) + ((set * 16 + bl) << 10) + nBase + nl],
                               h, __ATOMIC_RELAXED, __HIP_MEMORY_SCOPE_AGENT);
        }
        __syncthreads();                                   // bar2 (drains A pub)
        if (tid == 0 && ts < NT - 1)
            __hip_atomic_store(&sy[(set * 2 + 0) * 64 + rank], tgt,
                               __ATOMIC_RELAXED, __HIP_MEMORY_SCOPE_AGENT);

        // ================= octet B =================
        float preB = 0.f; TP* ppB = nullptr;
        if (tid < 128) {
            ppB = &P[((long)(set * 16 + 8 + bl) * NT + ts) * NH + nBase + nl];
            preB = load1<TP>(ppB);
        }
        {
            float acc[4][2] = {};
            #pragma unroll
            for (int kk = 0; kk < 8; ++kk) {
                f4 hv[4];
                #pragma unroll
                for (int i = 0; i < 4; ++i)
                    hv[i] = *(const f4*)&hsB[(tb * 4 + i) * HS_STR + tk * 32 + kk * 4];
                #pragma unroll
                for (int c = 0; c < 4; ++c)
                    #pragma unroll
                    for (int i = 0; i < 4; ++i) {
                        acc[i][0] += hv[i][c] * w0[kk * 4 + c];
                        acc[i][1] += hv[i][c] * w1[kk * 4 + c];
                    }
            }
            __syncthreads();                               // bar3 (A red-reads done)
            #pragma unroll
            for (int i = 0; i < 4; ++i) {
                red[tk * RD_STR + (tb * 4 + i) * 16 + tn * 2 + 0] = acc[i][0];
                red[tk * RD_STR + (tb * 4 + i) * 16 + tn * 2 + 1] = acc[i][1];
            }
        }
        __syncthreads();                                   // bar4
        if (tid < 128) {
            float s = 0.f;
            #pragma unroll
            for (int q = 0; q < 32; ++q) s += red[q * RD_STR + tid];
            const float h = fmaxf(s + preB, 0.f);
            store1<TP>(ppB, h);
            __hip_atomic_store(&Hring[((long)(ts & 1) << 16) + ((set * 16 + 8 + bl) << 10) + nBase + nl],
                               h, __ATOMIC_RELAXED, __HIP_MEMORY_SCOPE_AGENT);
        }
        if (ts == NT - 1) break;
        __syncthreads();                                   // bar5 (drains B pub)
        if (tid == 0)
            __hip_atomic_store(&sy[(set * 2 + 1) * 64 + rank], tgt,
                               __ATOMIC_RELAXED, __HIP_MEMORY_SCOPE_AGENT);

        // ============ poll both octets' 64 flags (lane-parallel) ============
        {
            const unsigned* fpA = &sy[(set * 2 + 0) * 64 + lane];
            const unsigned* fpB = &sy[(set * 2 + 1) * 64 + lane];
            for (;;) {
                unsigned a = __hip_atomic_load(fpA, __ATOMIC_RELAXED, __HIP_MEMORY_SCOPE_AGENT);
                unsigned b = __hip_atomic_load(fpB, __ATOMIC_RELAXED, __HIP_MEMORY_SCOPE_AGENT);
                if (__all((int)(a >= tgt && b >= tgt))) break;
                __builtin_amdgcn_s_sleep(1);
            }
        }

        // ============ stage h_t for both octets (sc0/sc1 LLC reads) ============
        {
            const float* hbA = Hring + ((long)(ts & 1) << 16) + ((long)(set * 16) << 10) + (tid << 1);
            const float* hbB = hbA + (8 << 10);
            f2 sA[8], sB[8];
            #pragma unroll
            for (int r = 0; r < 8; ++r)
                asm volatile("global_load_dwordx2 %0, %1, off sc0 sc1"
                             : "=v"(sA[r]) : "v"(hbA + (r << 10)) : "memory");
            #pragma unroll
            for (int r = 0; r < 8; ++r)
                asm volatile("global_load_dwordx2 %0, %1, off sc0 sc1"
                             : "=v"(sB[r]) : "v"(hbB + (r << 10)) : "memory");
            asm volatile("s_waitcnt vmcnt(0)" ::: "memory");
            #pragma unroll
            for (int r = 0; r < 8; ++r) {
                *(f2*)&hsA[r * HS_STR + (tid << 1)] = sA[r];
                *(f2*)&hsB[r * HS_STR + (tid << 1)] = sB[r];
            }
        }
        __syncthreads();                                   // bar6 (stage visible)
    }
}

// ===================== final FC on last timestep =====================
template <typename TP>
__global__ __launch_bounds__(128)
void fc_kernel(const TP* __restrict__ seq, const float* __restrict__ fcw,
               const float* __restrict__ fcb, float* __restrict__ out)
{
    __shared__ float hrow[NH];
    const int b = blockIdx.x, tid = threadIdx.x;
    for (int i = tid * 4; i < NH; i += 128 * 4) {
        f4 v = load4<TP>(&seq[((long)b * NT + (NT - 1)) * NH + i]);
        *(f4*)&hrow[i] = v;
    }
    __syncthreads();
    float s = 0.f;
    const float* wr = &fcw[tid * NH];
    for (int k = 0; k < NH; k += 4) {
        f4 w = *(const f4*)&wr[k];
        s += w[0] * hrow[k] + w[1] * hrow[k + 1] + w[2] * hrow[k + 2] + w[3] * hrow[k + 3];
    }
    out[b * DOUT + tid] = s + fcb[tid];
}

// ===================== launchers =====================
template <typename TP>
static void coop_recur(const float* W, TP* P, float* Hring, unsigned* sy,
                       hipStream_t stream)
{
    hipMemsetAsync(sy, 0, 4096, stream);
    const float* Wp = W; TP* Pp = P; float* H = Hring; unsigned* s = sy;
    void* args[4] = { &Wp, &Pp, &H, &s };
    hipLaunchCooperativeKernel((const void*)recur_kernel<TP>, dim3(256), dim3(512),
                               args, 0, stream);
}

static void run_pathA(const float* x, const float* wih0, const float* wihr,
                      const float* whh, const float* bih, const float* bhh,
                      const float* fcw, const float* fcb, float* out,
                      unsigned* sy, float* Hring, float* P0, float* P1,
                      hipStream_t stream)
{
    const dim3 blk(256);
    proj_kernel<DIN, 9, float, float><<<8192, blk, 0, stream>>>(x, wih0, bih, bhh, P0, 0);
    coop_recur<float>(whh, P0, Hring, sy, stream);
    proj_kernel<NH, 9, float, float><<<8192, blk, 0, stream>>>(P0, wihr,
        bih + NH, bhh + NH, P1, 0);
    coop_recur<float>(whh + NH * NH, P1, Hring, sy, stream);
    proj_kernel<NH, 9, float, float><<<8192, blk, 0, stream>>>(P1, wihr + NH * NH,
        bih + 2 * NH, bhh + 2 * NH, P0, 0);
    coop_recur<float>(whh + 2 * (NH * NH), P0, Hring, sy, stream);
    fc_kernel<float><<<dim3(NB), dim3(128), 0, stream>>>(P0, fcw, fcb, out);
}

template <typename TP>
static void run_pathBC(const float* x, const float* wih0, const float* wihr,
                       const float* whh, const float* bih, const float* bhh,
                       const float* fcw, const float* fcb, float* out,
                       unsigned* sy, float* Hring, TP* P, TP* Q, hipStream_t stream)
{
    const dim3 blk(256);
    proj_kernel<DIN, 9, float, TP><<<8192, blk, 0, stream>>>(x, wih0, bih, bhh, P, 0);
    coop_recur<TP>(whh, P, Hring, sy, stream);
    for (int l = 1; l < 3; ++l) {
        const float* wih = wihr + (long)(l - 1) * NH * NH;
        for (int c = 0; c < NT / 32; ++c) {
            proj_kernel<NH, 5, TP, TP><<<512, blk, 0, stream>>>(P, wih, bih + l * NH,
                                                                bhh + l * NH, Q, c * 32);
            copyback_kernel<TP, 5><<<NB * 32, blk, 0, stream>>>(Q, P, c * 32);
        }
        coop_recur<TP>(whh + (long)l * NH * NH, P, Hring, sy, stream);
    }
    fc_kernel<TP><<<dim3(NB), dim3(128), 0, stream>>>(P, fcw, fcb, out);
}

extern "C" void kernel_launch(void* const* d_in, const int* in_sizes, int n_in,
                              void* d_out, int out_size, void* d_ws, size_t ws_size,
                              hipStream_t stream)
{
    (void)in_sizes; (void)n_in; (void)out_size;
    const float* x    = (const float*)d_in[0];
    const float* wih0 = (const float*)d_in[1];
    const float* wihr = (const float*)d_in[2];
    const float* whh  = (const float*)d_in[3];
    const float* bih  = (const float*)d_in[4];
    const float* bhh  = (const float*)d_in[5];
    const float* fcw  = (const float*)d_in[6];
    const float* fcb  = (const float*)d_in[7];
    float* out = (float*)d_out;

    char* ws = (char*)d_ws;
    unsigned* sy = (unsigned*)ws;                         // 4 KB flags
    float* Hring = (float*)(ws + 4096);                   // 2 x 64x1024 fp32
    char* base = ws + 4096 + 2ull * NB * NH * 4;

    const size_t pF32 = (size_t)NB * NT * NH * 4;         // 128 MiB
    const size_t qF32 = (size_t)NB * 32 * NH * 4;         // 8 MiB
    const size_t head = 4096 + 2ull * NB * NH * 4;
    const size_t needA = head + 2 * pF32;                 // ~256.5 MiB
    const size_t needB = head + pF32 + qF32;              // ~136.5 MiB

    if (ws_size >= needA) {
        float* P0 = (float*)base;
        float* P1 = (float*)(base + pF32);
        run_pathA(x, wih0, wihr, whh, bih, bhh, fcw, fcb, out,
                  sy, Hring, P0, P1, stream);
    } else if (ws_size >= needB) {
        float* P = (float*)base;
        float* Q = (float*)(base + pF32);
        run_pathBC<float>(x, wih0, wihr, whh, bih, bhh, fcw, fcb, out,
                          sy, Hring, P, Q, stream);
    } else {
        bfr* P = (bfr*)base;
        bfr* Q = (bfr*)(base + pF32 / 2);
        run_pathBC<bfr>(x, wih0, wihr, whh, bih, bhh, fcw, fcb, out,
                        sy, Hring, P, Q, stream);
    }
}

// Round 6
// 10897.227 us; speedup vs baseline: 1.1287x; 1.1287x over previous
//
#include <hip/hip_runtime.h>

// RNNModel: B=64, T=512, D_IN=256, H=1024, L=3, D_OUT=128 (all fp32)
// R6: phase-shifted octet handoff. Publish each octet's h EARLY (right after its
//     reduce, per-wave flags via vmcnt(0)), poll/stage it LATE (after the other
//     octet's matvec) -> flag->poll gap spans a compute phase. 4 barriers/step.
//     hs skewed (+4 floats per 32-block) -> conflict-free matvec ds_read_b128.
#define NB   64
#define NT   512
#define DIN  256
#define NH   1024
#define DOUT 128

#define HS2_STR 1156   // 1024 + 4*(1024/32) skew + pad; mod 32 = 4 (row rotation)
#define RD_STR  136

typedef float f4 __attribute__((ext_vector_type(4)));
typedef unsigned short bfr;   // raw bf16 storage

__device__ __forceinline__ float b2f(bfr u) {
    union { unsigned u; float f; } v; v.u = ((unsigned)u) << 16; return v.f;
}
__device__ __forceinline__ bfr f2b(float f) {   // round-to-nearest-even
    union { float f; unsigned u; } v; v.f = f;
    unsigned r = v.u + 0x7FFFu + ((v.u >> 16) & 1u);
    return (bfr)(r >> 16);
}

template <typename T> __device__ __forceinline__ f4 load4(const T* p);
template <> __device__ __forceinline__ f4 load4<float>(const float* p) { return *(const f4*)p; }
template <> __device__ __forceinline__ f4 load4<bfr>(const bfr* p) {
    ushort4 u = *(const ushort4*)p;
    f4 r; r[0] = b2f(u.x); r[1] = b2f(u.y); r[2] = b2f(u.z); r[3] = b2f(u.w); return r;
}
template <typename T> __device__ __forceinline__ void store1(T* p, float v);
template <> __device__ __forceinline__ void store1<float>(float* p, float v) { *p = v; }
template <> __device__ __forceinline__ void store1<bfr>(bfr* p, float v) { *p = f2b(v); }
template <typename T> __device__ __forceinline__ float load1(const T* p);
template <> __device__ __forceinline__ float load1<float>(const float* p) { return *p; }
template <> __device__ __forceinline__ float load1<bfr>(const bfr* p) { return b2f(*p); }

// ===================== input projection GEMM (unchanged, passes) ===============
template <int K, int LOG2CT, typename TA, typename TO>
__global__ __launch_bounds__(256)
void proj_kernel(const TA* __restrict__ A, const float* __restrict__ W,
                 const float* __restrict__ bih, const float* __restrict__ bhh,
                 TO* __restrict__ out, int tOff)
{
    __shared__ float As[16][68];
    __shared__ float Ws[16][68];
    const int tid = threadIdx.x;
    const int CTM = (1 << LOG2CT) - 1;
    const int m0 = (blockIdx.x >> 4) << 6;
    const int n0 = (blockIdx.x & 15) << 6;
    const int tm = tid & 15, tn = tid >> 4;
    const int lr = tid >> 2, lc = tid & 3;

    const int rA = m0 + lr;
    const long mrowA = (long)(rA >> LOG2CT) * NT + tOff + (rA & CTM);

    float acc[4][4] = {};
    for (int k0 = 0; k0 < K; k0 += 16) {
        f4 av = load4<TA>(&A[mrowA * K + k0 + lc * 4]);
        f4 wv = *(const f4*)&W[(n0 + lr) * K + k0 + lc * 4];
        __syncthreads();
        #pragma unroll
        for (int j = 0; j < 4; ++j) {
            As[lc * 4 + j][lr] = av[j];
            Ws[lc * 4 + j][lr] = wv[j];
        }
        __syncthreads();
        #pragma unroll
        for (int k = 0; k < 16; ++k) {
            f4 a = *(const f4*)&As[k][tm * 4];
            f4 w = *(const f4*)&Ws[k][tn * 4];
            #pragma unroll
            for (int i = 0; i < 4; ++i)
                #pragma unroll
                for (int j = 0; j < 4; ++j)
                    acc[i][j] += a[i] * w[j];
        }
    }
    #pragma unroll
    for (int j = 0; j < 4; ++j) {
        const int n = n0 + tn * 4 + j;
        const float bias = bih[n] + bhh[n];
        #pragma unroll
        for (int i = 0; i < 4; ++i)
            store1<TO>(&out[(long)(m0 + tm * 4 + i) * NH + n], acc[i][j] + bias);
    }
}

// ===================== chunk copy-back (Paths B/C) =====================
template <typename TP, int L2CT>
__global__ __launch_bounds__(256)
void copyback_kernel(const TP* __restrict__ Q, TP* __restrict__ P, int tOff)
{
    const int r = blockIdx.x, tid = threadIdx.x;
    const int b = r >> L2CT, t = r & ((1 << L2CT) - 1);
    const TP* q = Q + (long)r * NH;
    TP* p = P + ((long)b * NT + tOff + t) * NH;
    #pragma unroll
    for (int j = 0; j < 4; ++j) p[tid + j * 256] = q[tid + j * 256];
}

// ===================== recurrent layer (cooperative, 256 WGs x 512 thr) =========
__device__ __forceinline__ void poll64(const unsigned* fl, unsigned tgt, int lane)
{
    const unsigned long long* fp = (const unsigned long long*)fl + lane;  // rank pair
    for (;;) {
        unsigned long long v = __hip_atomic_load(fp, __ATOMIC_RELAXED,
                                                 __HIP_MEMORY_SCOPE_AGENT);
        unsigned lo = (unsigned)v, hi = (unsigned)(v >> 32);
        if (__all((int)(lo >= tgt && hi >= tgt))) break;
        __builtin_amdgcn_s_sleep(1);
    }
}

template <typename TP>
__global__ __launch_bounds__(512)
void recur_kernel(const float* __restrict__ Whh, TP* __restrict__ P,
                  float* __restrict__ Hring, unsigned* __restrict__ sy)
{
    __shared__ float hsA[8 * HS2_STR];   // 36.1 KB, skewed h state octet A
    __shared__ float hsB[8 * HS2_STR];   // 36.1 KB, octet B
    __shared__ float red[32 * RD_STR];   // 17.0 KB, k-split partials (shared A/B)

    const int tid  = threadIdx.x;
    const int wg   = blockIdx.x;
    const int nBase = (wg & 63) << 4;
    const int set   = wg >> 6;
    const int rank  = wg & 63;
    const int lane  = tid & 63;
    const int tk = tid >> 4, tn = (tid >> 1) & 7, tb = tid & 1;  // matvec roles
    const int bl = tid >> 4, nl = tid & 15;                      // reduce roles (tid<128)
    const int srow = tid >> 6;                                   // stage row [0,8)
    const int sgOff = srow * NH + lane * 4;                      // global stage offset
    const int slOff = srow * HS2_STR + lane * 4 + ((lane >> 3) << 2);  // skewed LDS

    // per-octet bases
    unsigned* syA = sy + (set * 2 + 0) * 128;    // [rank][wave2] pairs
    unsigned* syB = sy + (set * 2 + 1) * 128;
    float* HrA = Hring + (long)(set * 16) * NH;  // + slot*65536
    float* HrB = HrA + 8 * NH;

    // W slice into registers: rows nBase+tn*2+{0,1}, cols [tk*32,+32)
    float w0[32], w1[32];
    {
        const float* p0 = &Whh[(nBase + tn * 2 + 0) * NH + tk * 32];
        const float* p1 = &Whh[(nBase + tn * 2 + 1) * NH + tk * 32];
        #pragma unroll
        for (int i = 0; i < 8; ++i) {
            *(f4*)&w0[i * 4] = *(const f4*)&p0[i * 4];
            *(f4*)&w1[i * 4] = *(const f4*)&p1[i * 4];
        }
    }
    for (int i = tid; i < 8 * HS2_STR; i += 512) { hsA[i] = 0.f; hsB[i] = 0.f; }
    __syncthreads();

    #pragma unroll 1
    for (int ts = 0; ts < NT; ++ts) {
        const int slot = (ts & 1) * (NB * NH);
        const int pslot = ((ts - 1) & 1) * (NB * NH);

        // prefetch pre for both octets (reducers)
        float preA = 0.f, preB = 0.f; TP *ppA = nullptr, *ppB = nullptr;
        if (tid < 128) {
            ppA = &P[((long)(set * 16 + bl) * NT + ts) * NH + nBase + nl];
            ppB = &P[((long)(set * 16 + 8 + bl) * NT + ts) * NH + nBase + nl];
            preA = load1<TP>(ppA);
            preB = load1<TP>(ppB);
        }

        // ---- 1. matvec A (hsA holds h_{ts-1}, octet A) ----
        float accA[4][2] = {};
        #pragma unroll
        for (int kk = 0; kk < 8; ++kk) {
            const int kko = tk * 36 + kk * 4;    // skewed k base
            f4 hv[4];
            #pragma unroll
            for (int i = 0; i < 4; ++i)
                hv[i] = *(const f4*)&hsA[(tb * 4 + i) * HS2_STR + kko];
            #pragma unroll
            for (int c = 0; c < 4; ++c)
                #pragma unroll
                for (int i = 0; i < 4; ++i) {
                    accA[i][0] += hv[i][c] * w0[kk * 4 + c];
                    accA[i][1] += hv[i][c] * w1[kk * 4 + c];
                }
        }

        // ---- 2. poll B(ts-1) + issue B stage loads (latency hides under 3-4) ----
        f4 sB[4];
        if (ts > 0) {
            poll64(syB, (unsigned)ts, lane);
            const float* src = HrB + pslot + sgOff;
            #pragma unroll
            for (int q = 0; q < 4; ++q)
                asm volatile("global_load_dwordx4 %0, %1, off sc0 sc1"
                             : "=v"(sB[q]) : "v"(src + q * 256) : "memory");
        }

        // ---- 3. write A partials ----
        #pragma unroll
        for (int i = 0; i < 4; ++i) {
            float* rp = &red[tk * RD_STR + (tb * 4 + i) * 16 + tn * 2];
            rp[0] = accA[i][0]; rp[1] = accA[i][1];
        }
        __syncthreads();                                    // bar1

        // ---- 4. reduce A, relu, publish + per-wave flag ----
        if (tid < 128) {
            float s = 0.f;
            #pragma unroll
            for (int q = 0; q < 32; ++q) s += red[q * RD_STR + tid];
            const float h = fmaxf(s + preA, 0.f);
            store1<TP>(ppA, h);
            __hip_atomic_store(&HrA[slot + bl * NH + nBase + nl], h,
                               __ATOMIC_RELAXED, __HIP_MEMORY_SCOPE_AGENT);
            if (ts < NT - 1) {
                asm volatile("s_waitcnt vmcnt(0)" ::: "memory");
                if (lane == 0)
                    __hip_atomic_store(&syA[rank * 2 + (tid >> 6)], (unsigned)(ts + 1),
                                       __ATOMIC_RELAXED, __HIP_MEMORY_SCOPE_AGENT);
            }
        }

        // ---- 5. stage B into LDS (sB ready after vmcnt) ----
        if (ts > 0) {
            asm volatile("s_waitcnt vmcnt(0)" ::: "memory");
            #pragma unroll
            for (int q = 0; q < 4; ++q)
                *(f4*)&hsB[slOff + q * 288] = sB[q];
        }
        __syncthreads();                                    // bar2

        // ---- 6. matvec B (hsB now h_{ts-1}, octet B) ----
        float accB[4][2] = {};
        #pragma unroll
        for (int kk = 0; kk < 8; ++kk) {
            const int kko = tk * 36 + kk * 4;
            f4 hv[4];
            #pragma unroll
            for (int i = 0; i < 4; ++i)
                hv[i] = *(const f4*)&hsB[(tb * 4 + i) * HS2_STR + kko];
            #pragma unroll
            for (int c = 0; c < 4; ++c)
                #pragma unroll
                for (int i = 0; i < 4; ++i) {
                    accB[i][0] += hv[i][c] * w0[kk * 4 + c];
                    accB[i][1] += hv[i][c] * w1[kk * 4 + c];
                }
        }

        // ---- 7. poll A(ts) + issue A stage loads (hides under 8-9) ----
        f4 sA[4];
        if (ts < NT - 1) {
            poll64(syA, (unsigned)(ts + 1), lane);
            const float* src = HrA + slot + sgOff;
            #pragma unroll
            for (int q = 0; q < 4; ++q)
                asm volatile("global_load_dwordx4 %0, %1, off sc0 sc1"
                             : "=v"(sA[q]) : "v"(src + q * 256) : "memory");
        }

        // ---- 8. write B partials (red reuse safe: bar2 after A reduce) ----
        #pragma unroll
        for (int i = 0; i < 4; ++i) {
            float* rp = &red[tk * RD_STR + (tb * 4 + i) * 16 + tn * 2];
            rp[0] = accB[i][0]; rp[1] = accB[i][1];
        }
        __syncthreads();                                    // bar3

        // ---- 9. reduce B, relu, publish + per-wave flag ----
        if (tid < 128) {
            float s = 0.f;
            #pragma unroll
            for (int q = 0; q < 32; ++q) s += red[q * RD_STR + tid];
            const float h = fmaxf(s + preB, 0.f);
            store1<TP>(ppB, h);
            __hip_atomic_store(&HrB[slot + bl * NH + nBase + nl], h,
                               __ATOMIC_RELAXED, __HIP_MEMORY_SCOPE_AGENT);
            if (ts < NT - 1) {
                asm volatile("s_waitcnt vmcnt(0)" ::: "memory");
                if (lane == 0)
                    __hip_atomic_store(&syB[rank * 2 + (tid >> 6)], (unsigned)(ts + 1),
                                       __ATOMIC_RELAXED, __HIP_MEMORY_SCOPE_AGENT);
            }
        }
        if (ts == NT - 1) break;

        // ---- 10. stage A into LDS (for matvecA of ts+1) ----
        asm volatile("s_waitcnt vmcnt(0)" ::: "memory");
        #pragma unroll
        for (int q = 0; q < 4; ++q)
            *(f4*)&hsA[slOff + q * 288] = sA[q];
        __syncthreads();                                    // bar4
    }
}

// ===================== final FC on last timestep =====================
template <typename TP>
__global__ __launch_bounds__(128)
void fc_kernel(const TP* __restrict__ seq, const float* __restrict__ fcw,
               const float* __restrict__ fcb, float* __restrict__ out)
{
    __shared__ float hrow[NH];
    const int b = blockIdx.x, tid = threadIdx.x;
    for (int i = tid * 4; i < NH; i += 128 * 4) {
        f4 v = load4<TP>(&seq[((long)b * NT + (NT - 1)) * NH + i]);
        *(f4*)&hrow[i] = v;
    }
    __syncthreads();
    float s = 0.f;
    const float* wr = &fcw[tid * NH];
    for (int k = 0; k < NH; k += 4) {
        f4 w = *(const f4*)&wr[k];
        s += w[0] * hrow[k] + w[1] * hrow[k + 1] + w[2] * hrow[k + 2] + w[3] * hrow[k + 3];
    }
    out[b * DOUT + tid] = s + fcb[tid];
}

// ===================== launchers =====================
template <typename TP>
static void coop_recur(const float* W, TP* P, float* Hring, unsigned* sy,
                       hipStream_t stream)
{
    hipMemsetAsync(sy, 0, 4096, stream);
    const float* Wp = W; TP* Pp = P; float* H = Hring; unsigned* s = sy;
    void* args[4] = { &Wp, &Pp, &H, &s };
    hipLaunchCooperativeKernel((const void*)recur_kernel<TP>, dim3(256), dim3(512),
                               args, 0, stream);
}

static void run_pathA(const float* x, const float* wih0, const float* wihr,
                      const float* whh, const float* bih, const float* bhh,
                      const float* fcw, const float* fcb, float* out,
                      unsigned* sy, float* Hring, float* P0, float* P1,
                      hipStream_t stream)
{
    const dim3 blk(256);
    proj_kernel<DIN, 9, float, float><<<8192, blk, 0, stream>>>(x, wih0, bih, bhh, P0, 0);
    coop_recur<float>(whh, P0, Hring, sy, stream);
    proj_kernel<NH, 9, float, float><<<8192, blk, 0, stream>>>(P0, wihr,
        bih + NH, bhh + NH, P1, 0);
    coop_recur<float>(whh + NH * NH, P1, Hring, sy, stream);
    proj_kernel<NH, 9, float, float><<<8192, blk, 0, stream>>>(P1, wihr + NH * NH,
        bih + 2 * NH, bhh + 2 * NH, P0, 0);
    coop_recur<float>(whh + 2 * (NH * NH), P0, Hring, sy, stream);
    fc_kernel<float><<<dim3(NB), dim3(128), 0, stream>>>(P0, fcw, fcb, out);
}

template <typename TP>
static void run_pathBC(const float* x, const float* wih0, const float* wihr,
                       const float* whh, const float* bih, const float* bhh,
                       const float* fcw, const float* fcb, float* out,
                       unsigned* sy, float* Hring, TP* P, TP* Q, hipStream_t stream)
{
    const dim3 blk(256);
    proj_kernel<DIN, 9, float, TP><<<8192, blk, 0, stream>>>(x, wih0, bih, bhh, P, 0);
    coop_recur<TP>(whh, P, Hring, sy, stream);
    for (int l = 1; l < 3; ++l) {
        const float* wih = wihr + (long)(l - 1) * NH * NH;
        for (int c = 0; c < NT / 32; ++c) {
            proj_kernel<NH, 5, TP, TP><<<512, blk, 0, stream>>>(P, wih, bih + l * NH,
                                                                bhh + l * NH, Q, c * 32);
            copyback_kernel<TP, 5><<<NB * 32, blk, 0, stream>>>(Q, P, c * 32);
        }
        coop_recur<TP>(whh + (long)l * NH * NH, P, Hring, sy, stream);
    }
    fc_kernel<TP><<<dim3(NB), dim3(128), 0, stream>>>(P, fcw, fcb, out);
}

extern "C" void kernel_launch(void* const* d_in, const int* in_sizes, int n_in,
                              void* d_out, int out_size, void* d_ws, size_t ws_size,
                              hipStream_t stream)
{
    (void)in_sizes; (void)n_in; (void)out_size;
    const float* x    = (const float*)d_in[0];
    const float* wih0 = (const float*)d_in[1];
    const float* wihr = (const float*)d_in[2];
    const float* whh  = (const float*)d_in[3];
    const float* bih  = (const float*)d_in[4];
    const float* bhh  = (const float*)d_in[5];
    const float* fcw  = (const float*)d_in[6];
    const float* fcb  = (const float*)d_in[7];
    float* out = (float*)d_out;

    char* ws = (char*)d_ws;
    unsigned* sy = (unsigned*)ws;                         // 4 KB flags
    float* Hring = (float*)(ws + 4096);                   // 2 x 64x1024 fp32
    char* base = ws + 4096 + 2ull * NB * NH * 4;

    const size_t pF32 = (size_t)NB * NT * NH * 4;         // 128 MiB
    const size_t qF32 = (size_t)NB * 32 * NH * 4;         // 8 MiB
    const size_t head = 4096 + 2ull * NB * NH * 4;
    const size_t needA = head + 2 * pF32;                 // ~256.5 MiB
    const size_t needB = head + pF32 + qF32;              // ~136.5 MiB

    if (ws_size >= needA) {
        float* P0 = (float*)base;
        float* P1 = (float*)(base + pF32);
        run_pathA(x, wih0, wihr, whh, bih, bhh, fcw, fcb, out,
                  sy, Hring, P0, P1, stream);
    } else if (ws_size >= needB) {
        float* P = (float*)base;
        float* Q = (float*)(base + pF32);
        run_pathBC<float>(x, wih0, wihr, whh, bih, bhh, fcw, fcb, out,
                          sy, Hring, P, Q, stream);
    } else {
        bfr* P = (bfr*)base;
        bfr* Q = (bfr*)(base + pF32 / 2);
        run_pathBC<bfr>(x, wih0, wihr, whh, bih, bhh, fcw, fcb, out,
                        sy, Hring, P, Q, stream);
    }
}